// Round 8
// baseline (169.271 us; speedup 1.0000x reference)
//
#include <hip/hip_runtime.h>
#include <stdint.h>

// Problem constants (fixed by reference setup_inputs):
//   qt:     (H=25920, S=64, D=64) f32
//   k:      (H, 1, D) f32          -- DEAD: softmax over singleton axis == 1
//   scaleb: (H, 1, 1) f32          -- DEAD: same reason
//   biasb:  (H, 1, 1) f32          -- zeros in setup; a5 = mask * biasb/keep
// out = qt + broadcast(a5) ; a5[h,s] = (bernoulli_keep ? 1/keep : 0) * biasb[h]
//
// R0: per-element biasb load + branch -> 175 us (4.85 TB/s).
// R1: serial scan kernel + global flag -> 202 us (regression).
// R2: per-head slab copy, wave-uniform biasb -> 163 us (5.2 TB/s).
// R4: + nontemporal load/store -> 150.6 us (5.64 TB/s).
// R5: 8-deep load/store batches -> 164.5 us (regression).
// R6: split copy + fixup kernels -> 158.9 us (copy alone == R4 rate; the
//     per-head branch was free; second dispatch costs ~8 us).
// R7: replace hand-written copy with runtime blit: hipMemcpyAsync D2D
//     (graph-legal memcpy node) + fixup kernel for biasb != 0.

#define NH 25920
#define NS 64
#define ND 64

typedef float f32x4 __attribute__((ext_vector_type(4)));

__device__ __forceinline__ uint32_t rotl32(uint32_t x, int n) {
  return (x << n) | (x >> (32 - n));
}

// JAX threefry2x32 with key = jax.random.key(42) -> (k0,k1) = (0,42).
__device__ __forceinline__ void threefry2x32_0_42(uint32_t x0, uint32_t x1,
                                                  uint32_t& y0, uint32_t& y1) {
  const uint32_t ks0 = 0u;
  const uint32_t ks1 = 42u;
  const uint32_t ks2 = 0u ^ 42u ^ 0x1BD11BDAu;
  x0 += ks0; x1 += ks1;
#define RND(r) { x0 += x1; x1 = rotl32(x1, (r)); x1 ^= x0; }
  RND(13) RND(15) RND(26) RND(6)
  x0 += ks1; x1 += ks2 + 1u;
  RND(17) RND(29) RND(16) RND(24)
  x0 += ks2; x1 += ks0 + 2u;
  RND(13) RND(15) RND(26) RND(6)
  x0 += ks0; x1 += ks1 + 3u;
  RND(17) RND(29) RND(16) RND(24)
  x0 += ks1; x1 += ks2 + 4u;
  RND(13) RND(15) RND(26) RND(6)
  x0 += ks2; x1 += ks0 + 5u;
#undef RND
  y0 = x0; y1 = x1;
}

// Fixup for biasb != 0 heads. One wave per head; all-zero biasb
// -> every wave early-exits after one broadcast load (~5 us total).
__global__ void __launch_bounds__(256)
fixup_kernel(const float* __restrict__ biasb, f32x4* __restrict__ out4) {
  const int wave = threadIdx.x >> 6;
  const int lane = threadIdx.x & 63;
  const int h = blockIdx.x * 4 + wave;
  const float b = biasb[h];          // same addr per wave -> broadcast
  if (b == 0.0f) return;             // wave-uniform
  // Exact JAX bernoulli(key(42), keep, (NH*NS,1)) for row = h*64 + lane.
  const float keep = 0.2021470392102155f;
  const uint32_t row = (uint32_t)((h << 6) + lane);
  const uint32_t n = (uint32_t)(NH * NS);
  const uint32_t half = n >> 1;
  uint32_t x0, x1, y0, y1;
  const bool hi = (row >= half);
  if (hi) { x0 = row - half; x1 = row; } else { x0 = row; x1 = row + half; }
  threefry2x32_0_42(x0, x1, y0, y1);
  const uint32_t bits = hi ? y1 : y0;
  const float u = __uint_as_float((bits >> 9) | 0x3F800000u) - 1.0f;
  if (u >= keep) return;             // dropped -> a5 row is 0, out already qt
  const float add = b / keep;        // softmax over singleton == 1
  f32x4* p = out4 + ((h << 10) + (lane << 4));  // this row's 16 float4
#pragma unroll
  for (int j = 0; j < 16; ++j) {
    f32x4 v = p[j];
    v.x += add; v.y += add; v.z += add; v.w += add;
    p[j] = v;
  }
}

extern "C" void kernel_launch(void* const* d_in, const int* in_sizes, int n_in,
                              void* d_out, int out_size, void* d_ws, size_t ws_size,
                              hipStream_t stream) {
  const void* qt = d_in[0];
  // d_in[1] = k (unused), d_in[2] = scaleb (unused)
  const float* biasb = (const float*)d_in[3];
  f32x4* out4 = (f32x4*)d_out;

  const size_t bytes = (size_t)NH * NS * ND * sizeof(float);  // 424.7 MB
  hipMemcpyAsync(d_out, qt, bytes, hipMemcpyDeviceToDevice, stream);
  fixup_kernel<<<NH / 4, 256, 0, stream>>>(biasb, out4);
}

// Round 9
// 161.074 us; speedup vs baseline: 1.0509x; 1.0509x over previous
//
#include <hip/hip_runtime.h>
#include <stdint.h>

// Problem constants (fixed by reference setup_inputs):
//   qt:     (H=25920, S=64, D=64) f32
//   k:      (H, 1, D) f32          -- DEAD: softmax over singleton axis == 1
//   scaleb: (H, 1, 1) f32          -- DEAD: same reason
//   biasb:  (H, 1, 1) f32          -- zeros in setup; a5 = mask * biasb/keep
// out = qt + broadcast(a5) ; a5[h,s] = (bernoulli_keep ? 1/keep : 0) * biasb[h]
//
// R0: per-element biasb load + branch -> 175 us (4.85 TB/s).
// R1: serial scan kernel + global flag -> 202 us (regression).
// R2: per-head slab copy, wave-uniform biasb, (normal,normal) -> 163 us.
// R4: + (nt-load, nt-store) -> 150.6 us (5.64 TB/s). BEST.
// R5: 8-deep load/store batches -> 164.5 us (regression).
// R6: split copy + fixup -> 158.9 us (copy alone == R4; branch is free).
// R7: hipMemcpyAsync blit -> 169.3 us (runtime copy slower than ours).
// R8: single variable on R4: (nt-load, NORMAL-store). Theory: nt stores
//     stream to HBM and interleave with reads (bus turnaround); normal
//     stores batch through L2 evictions. RFO would show as +425MB FETCH.

#define NH 25920
#define NS 64
#define ND 64
#define HEADS_PER_BLOCK 4

typedef float f32x4 __attribute__((ext_vector_type(4)));

__device__ __forceinline__ uint32_t rotl32(uint32_t x, int n) {
  return (x << n) | (x >> (32 - n));
}

// JAX threefry2x32 with key = jax.random.key(42) -> (k0,k1) = (0,42).
__device__ __forceinline__ void threefry2x32_0_42(uint32_t x0, uint32_t x1,
                                                  uint32_t& y0, uint32_t& y1) {
  const uint32_t ks0 = 0u;
  const uint32_t ks1 = 42u;
  const uint32_t ks2 = 0u ^ 42u ^ 0x1BD11BDAu;
  x0 += ks0; x1 += ks1;
#define RND(r) { x0 += x1; x1 = rotl32(x1, (r)); x1 ^= x0; }
  RND(13) RND(15) RND(26) RND(6)
  x0 += ks1; x1 += ks2 + 1u;
  RND(17) RND(29) RND(16) RND(24)
  x0 += ks2; x1 += ks0 + 2u;
  RND(13) RND(15) RND(26) RND(6)
  x0 += ks0; x1 += ks1 + 3u;
  RND(17) RND(29) RND(16) RND(24)
  x0 += ks1; x1 += ks2 + 4u;
  RND(13) RND(15) RND(26) RND(6)
  x0 += ks2; x1 += ks0 + 5u;
#undef RND
  y0 = x0; y1 = x1;
}

__global__ void __launch_bounds__(256)
fused_residual_kernel(const f32x4* __restrict__ qt4,
                      const float* __restrict__ biasb,
                      f32x4* __restrict__ out4) {
  const int h0 = blockIdx.x * HEADS_PER_BLOCK;
#pragma unroll
  for (int hh = 0; hh < HEADS_PER_BLOCK; ++hh) {
    const int h = h0 + hh;
    const float b = biasb[h];   // wave-uniform -> scalar load, 1 per 16 KB
    const int base = h << 10;   // 1024 float4 per head
    if (b == 0.0f) {
      // Hot path: nt loads (don't pollute L2/L3), NORMAL stores (batch
      // HBM writes via L2 eviction; full-line writes -> no RFO expected).
#pragma unroll
      for (int j = 0; j < 4; ++j) {
        const int idx = base + (j << 8) + threadIdx.x;
        f32x4 v = __builtin_nontemporal_load(&qt4[idx]);
        out4[idx] = v;
      }
    } else {
      // Robust fallback: exact JAX bernoulli(key(42), keep, (NH*NS,1)).
      const float keep = 0.2021470392102155f;
#pragma unroll
      for (int j = 0; j < 4; ++j) {
        const int t = (j << 8) + threadIdx.x;   // 0..1023 within slab
        const int idx = base + t;
        const uint32_t row = (uint32_t)((h << 6) + (t >> 4));  // global row
        const uint32_t n = (uint32_t)(NH * NS);
        const uint32_t half = n >> 1;
        uint32_t x0, x1, y0, y1;
        const bool hi = (row >= half);
        if (hi) { x0 = row - half; x1 = row; } else { x0 = row; x1 = row + half; }
        threefry2x32_0_42(x0, x1, y0, y1);
        const uint32_t bits = hi ? y1 : y0;
        const float u = __uint_as_float((bits >> 9) | 0x3F800000u) - 1.0f;
        const float add = (u < keep) ? (b / keep) : 0.0f;  // softmax(singleton)==1
        f32x4 v = __builtin_nontemporal_load(&qt4[idx]);
        v.x += add; v.y += add; v.z += add; v.w += add;
        out4[idx] = v;
      }
    }
  }
}

extern "C" void kernel_launch(void* const* d_in, const int* in_sizes, int n_in,
                              void* d_out, int out_size, void* d_ws, size_t ws_size,
                              hipStream_t stream) {
  const f32x4* qt4 = (const f32x4*)d_in[0];
  // d_in[1] = k (unused), d_in[2] = scaleb (unused)
  const float* biasb = (const float*)d_in[3];
  f32x4* out4 = (f32x4*)d_out;

  const int grid = NH / HEADS_PER_BLOCK;  // 6480 blocks, 4 heads (64 KB) each
  fused_residual_kernel<<<grid, 256, 0, stream>>>(qt4, biasb, out4);
}